// Round 4
// baseline (680.259 us; speedup 1.0000x reference)
//
#include <hip/hip_runtime.h>
#include <float.h>

// VectorQuantizer: N=262144 rows of D=64 fp32, K=1024 codebook rows.
// out = [x_quantized (N*D f32) | embed_inds (N, written as f32)]
//
// The np reference computes dis = fp32( fp32(x_norm + e_norm) - 2*sgemm_dot )
// with x_norm ~ 64 -> scores quantized to ulp(64)=7.6e-6 grid -> ~500 rows
// have exact fp32 ties, resolved by np.argmin as lowest index. We REPLICATE
// those fp32 semantics exactly (no f64, no "exact" argmin):
//   - dot: sequential FMA chain over d (OpenBLAS microkernel order)
//   - norms: numpy pairwise-8 accumulator pattern, mul-then-add (no fma)
//   - s = fadd(xn, en) then fmaf(-2, dot, t1)  [2*dot is exact]
//   - strict < scan ascending k = first-min tie-break

static constexpr int D_DIM = 64;
static constexpr int K_CB  = 1024;
static constexpr int TPB   = 128;      // 1 thread = 1 row

// numpy pairwise sum, n=64 path: 8 accumulators, sequential adds, fixed tree.
__device__ __forceinline__ float np_sum64_sq(const float* v) {
    float r[8];
#pragma unroll
    for (int j = 0; j < 8; ++j) r[j] = __fmul_rn(v[j], v[j]);
#pragma unroll
    for (int i = 8; i < 64; i += 8)
#pragma unroll
        for (int j = 0; j < 8; ++j) r[j] = __fadd_rn(r[j], __fmul_rn(v[i + j], v[i + j]));
    float t01 = __fadd_rn(r[0], r[1]), t23 = __fadd_rn(r[2], r[3]);
    float t45 = __fadd_rn(r[4], r[5]), t67 = __fadd_rn(r[6], r[7]);
    return __fadd_rn(__fadd_rn(t01, t23), __fadd_rn(t45, t67));
}

__global__ void __launch_bounds__(TPB) vq_kernel(
        const float* __restrict__ x, const float* __restrict__ cb,
        float* __restrict__ out_q, float* __restrict__ out_idx) {
    __shared__ float es[K_CB];     // e_norm (numpy-pattern fp32), 4 KB
    __shared__ int bks[TPB];

    const int tid = threadIdx.x;
    const size_t row0 = (size_t)blockIdx.x * TPB;
    const size_t row  = row0 + tid;
    const float4* cb4 = reinterpret_cast<const float4*>(cb);

    // --- block-local e_norm[k], numpy pairwise-8 pattern ---
    for (int k = tid; k < K_CB; k += TPB) {
        float cr[D_DIM];
        const float4* c4 = cb4 + k * 16;
#pragma unroll
        for (int c = 0; c < 16; ++c) {
            float4 v = c4[c];
            cr[4 * c + 0] = v.x; cr[4 * c + 1] = v.y;
            cr[4 * c + 2] = v.z; cr[4 * c + 3] = v.w;
        }
        es[k] = np_sum64_sq(cr);
    }
    __syncthreads();

    // --- my row -> 64 VGPRs; x_norm numpy-pattern ---
    float xr[D_DIM];
    const float4* xg = reinterpret_cast<const float4*>(x + row * D_DIM);
#pragma unroll
    for (int c = 0; c < 16; ++c) {
        float4 v = xg[c];
        xr[4 * c + 0] = v.x; xr[4 * c + 1] = v.y;
        xr[4 * c + 2] = v.z; xr[4 * c + 3] = v.w;
    }
    const float xn = np_sum64_sq(xr);

    // --- fp32 scan replicating np dis_mat rounding; strict < = first-min ---
    float best = FLT_MAX;
    int bestk = 0;
#pragma unroll 2
    for (int k = 0; k < K_CB; ++k) {
        const float4* cr = cb4 + k * 16;   // wave-uniform -> scalar/cached loads
        float dot = 0.f;                   // sequential FMA chain = sgemm order
#pragma unroll
        for (int c = 0; c < 16; ++c) {
            float4 v = cr[c];
            dot = __fmaf_rn(v.x, xr[4 * c + 0], dot);
            dot = __fmaf_rn(v.y, xr[4 * c + 1], dot);
            dot = __fmaf_rn(v.z, xr[4 * c + 2], dot);
            dot = __fmaf_rn(v.w, xr[4 * c + 3], dot);
        }
        float t1 = __fadd_rn(xn, es[k]);          // fl(x_norm + e_norm)
        float s  = __fmaf_rn(-2.0f, dot, t1);     // fl(t1 - 2*dot), 2*dot exact
        if (s < best) { best = s; bestk = k; }
    }

    bks[tid] = bestk;
    __syncthreads();

    // --- coalesced gather-write of x_quantized ---
    float4* oq = reinterpret_cast<float4*>(out_q + row0 * D_DIM);
#pragma unroll
    for (int j = 0; j < 16; ++j) {
        int f = tid + TPB * j;
        int r = f >> 4;
        int c = f & 15;
        oq[f] = cb4[(size_t)bks[r] * 16 + c];
    }
    out_idx[row] = (float)bestk;
}

extern "C" void kernel_launch(void* const* d_in, const int* in_sizes, int n_in,
                              void* d_out, int out_size, void* d_ws, size_t ws_size,
                              hipStream_t stream) {
    const float* x  = (const float*)d_in[0];
    const float* cb = (const float*)d_in[1];
    const int n_rows = in_sizes[0] / D_DIM;     // 262144

    float* out_q   = (float*)d_out;
    float* out_idx = out_q + (size_t)n_rows * D_DIM;

    vq_kernel<<<n_rows / TPB, TPB, 0, stream>>>(x, cb, out_q, out_idx);
}